// Round 17
// baseline (446.536 us; speedup 1.0000x reference)
//
#include <hip/hip_runtime.h>
#include <stdint.h>
#include <stddef.h>

// ---------------------------------------------------------------------------
// BayesFilter: B=8192, T=128, X=32, U=8, Z=3, W=6, H=128, M=16
//  Round-17: K4 zxu/zuw double-buffered (parity t&1); z-independent staging
//  (x/u slices) moved into interval 1 (overlaps GEMM1/GEMM2); interval 3 keeps
//  only the 4 z-dependent writes. K2 warmup 64->40 (104 steps).
//  K1/K3 unchanged (round-16).
// ---------------------------------------------------------------------------

typedef __fp16 half2_t __attribute__((ext_vector_type(2)));
typedef __fp16 f16x8_t __attribute__((ext_vector_type(8)));
typedef float  f32x4_t __attribute__((ext_vector_type(4)));

__device__ __forceinline__ float rcp_f(float x){
#if __has_builtin(__builtin_amdgcn_rcpf)
  return __builtin_amdgcn_rcpf(x);
#else
  return 1.0f/x;
#endif
}
__device__ __forceinline__ float exp2_f(float x){
#if __has_builtin(__builtin_amdgcn_exp2f)
  return __builtin_amdgcn_exp2f(x);
#else
  return exp2f(x);
#endif
}
__device__ __forceinline__ float log2_f(float x){
#if __has_builtin(__builtin_amdgcn_logf)
  return __builtin_amdgcn_logf(x);
#else
  return log2f(x);
#endif
}
__device__ __forceinline__ float sigmoid_f(float x){
  return rcp_f(1.0f + exp2_f(-1.4426950408889634f*x));
}
__device__ __forceinline__ float tanh_f(float x){
  x = fminf(fmaxf(x, -15.f), 15.f);
  float t = exp2_f(2.8853900817779268f*x);
  return (t - 1.0f)*rcp_f(t + 1.0f);
}
__device__ __forceinline__ float softplus_f(float x){
  float e = exp2_f(1.4426950408889634f*x);
  float r = 0.6931471805599453f*log2_f(1.0f + e);
  return (x > 15.f) ? x : r;
}
__device__ __forceinline__ unsigned pk(float a, float b){
  union { half2_t h; unsigned u; } cv;
#if __has_builtin(__builtin_amdgcn_cvt_pkrtz)
  cv.h = __builtin_amdgcn_cvt_pkrtz(a, b);
#else
  cv.h.x = (__fp16)a; cv.h.y = (__fp16)b;
#endif
  return cv.u;
}
__device__ __forceinline__ float fdot2_f(unsigned wa, unsigned va, float c){
  union { unsigned u; half2_t h; } A, B;
  A.u = wa; B.u = va;
#if __has_builtin(__builtin_amdgcn_fdot2)
  return __builtin_amdgcn_fdot2(A.h, B.h, c, false);
#else
  return c + (float)A.h.x*(float)B.h.x + (float)A.h.y*(float)B.h.y;
#endif
}
__device__ __forceinline__ float dot4u(uint4 w, uint4 v, float acc){
  acc = fdot2_f(w.x, v.x, acc);
  acc = fdot2_f(w.y, v.y, acc);
  acc = fdot2_f(w.z, v.z, acc);
  acc = fdot2_f(w.w, v.w, acc);
  return acc;
}
__device__ __forceinline__ uint4 ldsu4(const unsigned* p){ return *(const uint4*)p; }
__device__ __forceinline__ f32x4_t mfma16(uint4 a, uint4 b, f32x4_t c){
  union { uint4 u; f16x8_t h; } A, B;
  A.u = a; B.u = b;
  return __builtin_amdgcn_mfma_f32_16x16x32_f16(A.h, B.h, c, 0, 0, 0);
}
__device__ __forceinline__ uint4 pk8(const float* p){
  return make_uint4(pk(p[0],p[1]), pk(p[2],p[3]), pk(p[4],p[5]), pk(p[6],p[7]));
}

#define NB 8192
#define NT 128

// ---------------------------------------------------------------------------
// K1: input projection. 64-row tiles -> 256 blocks.
// ---------------------------------------------------------------------------
__global__ __launch_bounds__(384) void k1_pre(
    const float* __restrict__ x,
    const float* __restrict__ Wi_f, const float* __restrict__ bi_f, const float* __restrict__ bh_f,
    const float* __restrict__ Wi_b, const float* __restrict__ bi_b, const float* __restrict__ bh_b,
    float* __restrict__ pre_f, float* __restrict__ pre_b)
{
  const int tid = threadIdx.x;
  const int dir = blockIdx.y;
  const int tile = blockIdx.x;
  const float* Wi = dir ? Wi_b : Wi_f;
  const float* bi = dir ? bi_b : bi_f;
  const float* bh = dir ? bh_b : bh_f;
  float* pre = dir ? pre_b : pre_f;

  float w[32];
  #pragma unroll
  for(int c=0;c<8;c++){
    float4 a = *(const float4*)&Wi[tid*32 + 4*c];
    w[4*c+0]=a.x; w[4*c+1]=a.y; w[4*c+2]=a.z; w[4*c+3]=a.w;
  }
  float bias = bi[tid] + ((tid < 256) ? bh[tid] : 0.f);

  __shared__ __align__(16) float xs[64][32];
  for(int idx = tid; idx < 2048; idx += 384){
    int rr = idx >> 5, k = idx & 31;
    int i = tile*64 + rr;
    int src = dir ? (NB-1 - i) : i;
    xs[rr][k] = x[(size_t)src*4096 + k];
  }
  __syncthreads();

  for(int rr=0; rr<64; rr++){
    float acc = bias;
    #pragma unroll
    for(int c=0;c<8;c++){
      float4 xv = *(const float4*)&xs[rr][4*c];
      acc += xv.x*w[4*c] + xv.y*w[4*c+1] + xv.z*w[4*c+2] + xv.w*w[4*c+3];
    }
    pre[(size_t)(tile*64+rr)*384 + tid] = acc;
  }
}

// ---------------------------------------------------------------------------
// K2: GRU chunks. O=64, W=40 -> 128 chunks/dir (256 blocks), 104 steps.
// ---------------------------------------------------------------------------
__global__ __launch_bounds__(512, 4) void k2_gru(
    const float* __restrict__ pre_f, const float* __restrict__ pre_b,
    const float* __restrict__ Wh_f, const float* __restrict__ Wh_b,
    const float* __restrict__ bh_f, const float* __restrict__ bh_b,
    float* __restrict__ hs_f, float* __restrict__ hs_b)
{
  const int tid = threadIdx.x;
  const int dir = blockIdx.y;
  const int chunk = blockIdx.x;
  const float* pre = dir ? pre_b : pre_f;
  const float* Wh  = dir ? Wh_b  : Wh_f;
  const float* bh  = dir ? bh_b  : bh_f;
  float* hs = dir ? hs_b : hs_f;

  const int j = tid >> 2;
  const int q = tid & 3;
  const int i_begin = chunk*64;
  int i0 = i_begin - 40; if(i0 < 0) i0 = 0;
  const int i1 = i_begin + 64;

  unsigned wrp[16], wzp[16], wnp[16];
  #pragma unroll
  for(int c=0;c<8;c++){
    float4 a = *(const float4*)&Wh[(size_t)(j      )*128 + 32*q + 4*c];
    float4 b = *(const float4*)&Wh[(size_t)(128 + j)*128 + 32*q + 4*c];
    float4 d = *(const float4*)&Wh[(size_t)(256 + j)*128 + 32*q + 4*c];
    wrp[2*c]   = pk(a.x, a.y); wrp[2*c+1] = pk(a.z, a.w);
    wzp[2*c]   = pk(b.x, b.y); wzp[2*c+1] = pk(b.z, b.w);
    wnp[2*c]   = pk(d.x, d.y); wnp[2*c+1] = pk(d.z, d.w);
  }
  const float bhn = bh[256 + j];

  __shared__ __align__(16) unsigned short hbuf16[2][128];
  __shared__ __align__(16) float pbuf[3][384];
  if(tid < 128) hbuf16[0][tid] = 0;
  if(tid < 384){
    pbuf[0][tid] = pre[(size_t)i0*384 + tid];
    pbuf[1][tid] = pre[(size_t)(i0+1)*384 + tid];
  }
  float h_old = 0.f;
  __syncthreads();

  #pragma unroll 1
  for(int s = i0; s < i1; ++s){
    const int k = s - i0;
    const int cur = k & 1;
    const int p3 = k % 3;
    float pf = 0.f;
    const bool dopf = (tid < 384) && (s+2 < i1);
    if(dopf) pf = pre[(size_t)(s+2)*384 + tid];

    const unsigned* hquart = (const unsigned*)&hbuf16[cur][0] + 16*q;
    uint4 h0 = ldsu4(hquart), h1 = ldsu4(hquart+4), h2 = ldsu4(hquart+8), h3 = ldsu4(hquart+12);

    float ar=0.f, az=0.f, an=0.f;
    ar = dot4u(*(uint4*)&wrp[0], h0, ar); ar = dot4u(*(uint4*)&wrp[4],  h1, ar);
    ar = dot4u(*(uint4*)&wrp[8], h2, ar); ar = dot4u(*(uint4*)&wrp[12], h3, ar);
    az = dot4u(*(uint4*)&wzp[0], h0, az); az = dot4u(*(uint4*)&wzp[4],  h1, az);
    az = dot4u(*(uint4*)&wzp[8], h2, az); az = dot4u(*(uint4*)&wzp[12], h3, az);
    an = dot4u(*(uint4*)&wnp[0], h0, an); an = dot4u(*(uint4*)&wnp[4],  h1, an);
    an = dot4u(*(uint4*)&wnp[8], h2, an); an = dot4u(*(uint4*)&wnp[12], h3, an);

    ar += __shfl_xor(ar, 1, 64); ar += __shfl_xor(ar, 2, 64);
    az += __shfl_xor(az, 1, 64); az += __shfl_xor(az, 2, 64);
    an += __shfl_xor(an, 1, 64); an += __shfl_xor(an, 2, 64);

    float prv = pbuf[p3][j];
    float pzv = pbuf[p3][128 + j];
    float pnv = pbuf[p3][256 + j];
    float r  = sigmoid_f(prv + ar);
    float zg = sigmoid_f(pzv + az);
    float n  = tanh_f(pnv + r*(an + bhn));
    float hnew = n + zg*(h_old - n);
    h_old = hnew;

    if(q == 0){
      union { __fp16 h; unsigned short u; } cv; cv.h = (__fp16)hnew;
      hbuf16[cur^1][j] = cv.u;
      if(s >= i_begin){
        int row = dir ? (NB-1 - s) : s;
        hs[(size_t)row*128 + j] = hnew;
      }
    }
    if(dopf) pbuf[(k+2)%3][tid] = pf;
    __syncthreads();
  }
}

// ---------------------------------------------------------------------------
// K3: t=0 head (unchanged from round-16: pxi via MFMA).
// ---------------------------------------------------------------------------
__global__ __launch_bounds__(512) void k3_head(
    const float* __restrict__ hs_f, const float* __restrict__ hs_b,
    const float* __restrict__ pxi_W, const float* __restrict__ pxi_b,
    const float* __restrict__ mu_W, const float* __restrict__ mu_b,
    const float* __restrict__ sg_W, const float* __restrict__ sg_b,
    const float* __restrict__ eps_w1,
    const float* __restrict__ pl_W1, const float* __restrict__ pl_b1,
    const float* __restrict__ pl_W2, const float* __restrict__ pl_b2,
    const float* __restrict__ pth_W1, const float* __restrict__ pth_b1,
    const float* __restrict__ pth_W2, const float* __restrict__ pth_b2,
    float* __restrict__ out_x, float* __restrict__ out_w, float* __restrict__ out_z,
    float* __restrict__ z0ws)
{
  __shared__ __align__(16) unsigned hb16[32][132];
  __shared__ __align__(16) float h1[32][132];
  __shared__ __align__(16) float sW_pl1[128][8];
  __shared__ __align__(16) float sW_pt1[128][4];
  __shared__ __align__(16) float wbuf[32][8];
  __shared__ float sb_mu[6], sb_sg[6], sb_pl1[128], sb_pl2[3], sb_pt1[128], sb_pt2[32];

  const int tid = threadIdx.x;
  const int bbase = blockIdx.x*32;
  const int wv = tid >> 6;
  const int ln = tid & 63;
  const int lr = ln & 15;
  const int lq = ln >> 4;

  for(int idx=tid; idx<4096; idx+=512){
    int bb = idx>>7, p = idx&127;
    int c0 = 2*p, c1 = c0+1;
    const size_t base = (size_t)(bbase+bb)*128;
    float a = (c0<128) ? hs_f[base + c0] : hs_b[base + (c0-128)];
    float c = (c1<128) ? hs_f[base + c1] : hs_b[base + (c1-128)];
    hb16[bb][p] = pk(a, c);
  }
  uint4 Apx[8];
  #pragma unroll
  for(int ks=0;ks<8;ks++)
    Apx[ks] = pk8(pxi_W + (size_t)(16*wv + lr)*256 + ks*32 + lq*8);
  float pxb[4];
  #pragma unroll
  for(int rg=0;rg<4;rg++) pxb[rg] = pxi_b[16*wv + lq*4 + rg];

  for(int idx=tid; idx<1024; idx+=512){ int r = idx>>3, c = idx&7; sW_pl1[r][c] = (c<6)? pl_W1[r*6+c] : 0.f; }
  { int r = tid>>2, c = tid&3; sW_pt1[r][c] = (c<3)? pth_W1[r*3+c] : 0.f; }
  if(tid<128){ sb_pl1[tid]=pl_b1[tid]; sb_pt1[tid]=pth_b1[tid]; }
  if(tid<6){ sb_mu[tid]=mu_b[tid]; sb_sg[tid]=sg_b[tid]; }
  if(tid<3) sb_pl2[tid]=pl_b2[tid];
  if(tid<32) sb_pt2[tid]=pth_b2[tid];
  __syncthreads();

  {
    #pragma unroll
    for(int ct=0;ct<2;ct++){
      f32x4_t acc = {0.f,0.f,0.f,0.f};
      #pragma unroll
      for(int ks=0;ks<8;ks++)
        acc = mfma16(Apx[ks], ldsu4(&hb16[16*ct + lr][ks*16 + lq*4]), acc);
      const int e = 16*ct + lr;
      #pragma unroll
      for(int rg=0;rg<4;rg++)
        h1[e][16*wv + lq*4 + rg] = fmaxf(acc[rg] + pxb[rg], 0.f);
    }
  }
  __syncthreads();

  const int g = tid >> 4;
  const int j = tid & 15;
  const int b = bbase + g;

  float muv = 0.f, sgv = 0.f;
  if(j < 12){
    bool isS = (j >= 6); int o = isS ? (j-6) : j;
    const float4* wrow = (const float4*)((isS ? sg_W : mu_W) + (size_t)o*128);
    const float4* hrow = (const float4*)&h1[g][0];
    float acc = isS ? sb_sg[o] : sb_mu[o];
    #pragma unroll 8
    for(int kk=0;kk<32;kk++){
      float4 wv_ = wrow[kk], hv = hrow[kk];
      acc += wv_.x*hv.x + wv_.y*hv.y + wv_.z*hv.z + wv_.w*hv.w;
    }
    if(isS) sgv = softplus_f(acc); else muv = acc;
  }
  const int lw = tid & 63; const int gb = lw & 48;
  int src = gb + ((j < 6) ? (j + 6) : j);
  float sgp = __shfl(sgv, src, 64);
  if(j < 6){
    float w1v = muv + sgp*eps_w1[(size_t)b*6 + j];
    wbuf[g][j] = w1v;
    out_w[(size_t)b*1536 + j*2]     = muv;
    out_w[(size_t)b*1536 + j*2 + 1] = sgp;
  }
  if(j == 6 || j == 7) wbuf[g][j] = 0.f;

  {
    const float4* wb = (const float4*)&wbuf[g][0];
    float4 b0 = wb[0], b1 = wb[1];
    #pragma unroll
    for(int m=0;m<8;m++){
      int r = 8*j + m;
      float4 w0 = *(const float4*)&sW_pl1[r][0];
      float4 w1 = *(const float4*)&sW_pl1[r][4];
      h1[g][r] = sb_pl1[r]
        + w0.x*b0.x + w0.y*b0.y + w0.z*b0.z + w0.w*b0.w
        + w1.x*b1.x + w1.y*b1.y + w1.z*b1.z + w1.w*b1.w;
    }
  }
  float z0v = 0.f;
  if(j < 3){
    const float4* wrow = (const float4*)(pl_W2 + (size_t)j*128);
    const float4* hrow = (const float4*)&h1[g][0];
    float acc = sb_pl2[j];
    #pragma unroll 8
    for(int kk=0;kk<32;kk++){
      float4 wv_ = wrow[kk], hv = hrow[kk];
      acc += wv_.x*hv.x + wv_.y*hv.y + wv_.z*hv.z + wv_.w*hv.w;
    }
    z0v = acc;
    out_z[(size_t)b*384 + j] = z0v;
    z0ws[(size_t)b*3 + j] = z0v;
  }
  float zz0 = __shfl(z0v, gb+0, 64);
  float zz1 = __shfl(z0v, gb+1, 64);
  float zz2 = __shfl(z0v, gb+2, 64);
  #pragma unroll
  for(int m=0;m<8;m++){
    int r = 8*j + m;
    float4 wv_ = *(const float4*)&sW_pt1[r][0];
    h1[g][r] = sb_pt1[r] + wv_.x*zz0 + wv_.y*zz1 + wv_.z*zz2;
  }
  {
    float a1 = sb_pt2[j], a2 = sb_pt2[j+16];
    const float4* hrow = (const float4*)&h1[g][0];
    const float4* wA = (const float4*)(pth_W2 + (size_t)j*128);
    const float4* wB = (const float4*)(pth_W2 + (size_t)(j+16)*128);
    #pragma unroll 8
    for(int kk=0;kk<32;kk++){
      float4 hv = hrow[kk]; float4 a = wA[kk]; float4 c = wB[kk];
      a1 += a.x*hv.x + a.y*hv.y + a.z*hv.z + a.w*hv.w;
      a2 += c.x*hv.x + c.y*hv.y + c.z*hv.z + c.w*hv.w;
    }
    out_x[(size_t)b*4096 + j]      = a1;
    out_x[(size_t)b*4096 + j + 16] = a2;
  }
}

// ---------------------------------------------------------------------------
// K4: t = 1..127 scan. 256 blocks x 512 threads; 32 elems/block; 3 barriers.
// zxu/zuw double-buffered (parity p=t&1): x/u staging in interval 1,
// z-dependent staging (4 writes) in interval 3.
// ---------------------------------------------------------------------------
struct __align__(16) K4LDS {
  unsigned zxu[2][32][36];
  unsigned zuw[2][32][12];
  unsigned h1F[32][68];
  unsigned h1M[32][68];
  unsigned h1S[32][68];
  unsigned t2b[32][68];
  float alphaE[32][21];
  float wmws[32][21];
  float wbuf[32][8];
};
static_assert(sizeof(K4LDS) <= 65536, "K4 LDS over 64KB");

__global__ __launch_bounds__(512) void k4_scan(
    const float* __restrict__ x, const float* __restrict__ u, const float* __restrict__ eps_w,
    const float* __restrict__ z0ws,
    const float* __restrict__ fpsi_W1, const float* __restrict__ fpsi_b1,
    const float* __restrict__ fpsi_W2, const float* __restrict__ fpsi_b2,
    const float* __restrict__ qA, const float* __restrict__ qB, const float* __restrict__ qC,
    const float* __restrict__ qm_W1, const float* __restrict__ qm_b1,
    const float* __restrict__ qm_W2, const float* __restrict__ qm_b2,
    const float* __restrict__ qs_W1, const float* __restrict__ qs_b1,
    const float* __restrict__ qs_W2, const float* __restrict__ qs_b2,
    const float* __restrict__ pth_W1, const float* __restrict__ pth_b1,
    const float* __restrict__ pth_W2, const float* __restrict__ pth_b2,
    float* __restrict__ out_x, float* __restrict__ out_w, float* __restrict__ out_z)
{
  __shared__ K4LDS S;
  const int tid = threadIdx.x;
  const int jl = tid & 15;
  const int wv = tid >> 6;
  const int ln = tid & 63;
  const int lr = ln & 15;
  const int lq = ln >> 4;

  {
    { unsigned* z1 = &S.zxu[0][0][0]; for(int idx=tid; idx<2*32*36; idx+=512) z1[idx] = 0u; }
    { unsigned* z2 = &S.zuw[0][0][0]; for(int idx=tid; idx<2*32*12; idx+=512) z2[idx] = 0u; }
  }

  auto stackA = [&](int R, int k)->float{
    if(k >= 43) return 0.f;
    if(R < 128){
      if(k < 3)   return fpsi_W1[R*11 + k];
      if(k >= 35) return fpsi_W1[R*11 + 3 + (k - 35)];
      return 0.f;
    }
    if(R < 256) return qm_W1[(size_t)(R-128)*43 + k];
    return qs_W1[(size_t)(R-256)*43 + k];
  };
  uint4 A1[3][2]; float bias1[3][4];
  #pragma unroll
  for(int rt=0;rt<3;rt++){
    const int R0 = 48*wv + 16*rt;
    #pragma unroll
    for(int ks=0;ks<2;ks++){
      float f[8];
      #pragma unroll
      for(int e2=0;e2<8;e2++) f[e2] = stackA(R0 + lr, 32*ks + lq*8 + e2);
      A1[rt][ks] = make_uint4(pk(f[0],f[1]),pk(f[2],f[3]),pk(f[4],f[5]),pk(f[6],f[7]));
    }
    #pragma unroll
    for(int rg=0;rg<4;rg++){
      int R = R0 + lq*4 + rg;
      bias1[rt][rg] = (R<128) ? fpsi_b1[R] : (R<256 ? qm_b1[R-128] : qs_b1[R-256]);
    }
  }
  uint4 A2[4] = {};
  float b2v[4] = {0.f,0.f,0.f,0.f};
  {
    const int role2 = wv >> 1;
    if(role2 == 0){
      const float* wr_ = fpsi_W2 + (size_t)lr*128;
      #pragma unroll
      for(int ks=0;ks<4;ks++) A2[ks] = pk8(wr_ + ks*32 + lq*8);
      #pragma unroll
      for(int rg=0;rg<4;rg++) b2v[rg] = fpsi_b2[lq*4+rg];
    } else if(role2 == 1){
      if(lr < 6){
        const float* wr_ = qm_W2 + (size_t)lr*128;
        #pragma unroll
        for(int ks=0;ks<4;ks++) A2[ks] = pk8(wr_ + ks*32 + lq*8);
      }
      #pragma unroll
      for(int rg=0;rg<4;rg++){ int row = lq*4+rg; b2v[rg] = (row<6)? qm_b2[row] : 0.f; }
    } else if(role2 == 2){
      if(lr < 6){
        const float* wr_ = qs_W2 + (size_t)lr*128;
        #pragma unroll
        for(int ks=0;ks<4;ks++) A2[ks] = pk8(wr_ + ks*32 + lq*8);
      }
      #pragma unroll
      for(int rg=0;rg<4;rg++){ int row = lq*4+rg; b2v[rg] = (row<6)? qs_b2[row] : 0.f; }
    }
  }
  const int prt = wv & 1, pct = (wv >> 1) & 1;
  uint4 Ap[4] = {};
  float pb2r[4] = {0.f,0.f,0.f,0.f};
  if(wv < 4){
    #pragma unroll
    for(int ks=0;ks<4;ks++){
      const float* wr_ = pth_W2 + (size_t)(16*prt + lr)*128 + ks*32 + lq*8;
      Ap[ks] = pk8(wr_);
    }
    #pragma unroll
    for(int rg=0;rg<4;rg++) pb2r[rg] = pth_b2[16*prt + lq*4 + rg];
  }
  uint2 pw1[8]; float pb1v[8];
  #pragma unroll
  for(int m=0;m<8;m++){
    const float* prow = pth_W1 + (size_t)(8*jl + m)*3;
    pw1[m] = make_uint2(pk(prow[0],prow[1]), pk(prow[2],0.f));
    pb1v[m] = pth_b1[8*jl + m];
  }
  uint4 qzw[3][2]; unsigned qzt[3];
  {
    const int m = jl;
    #pragma unroll
    for(int i=0;i<3;i++){
      auto qv = [&](int e)->float{
        if(e < 3)  return qA[m*9  + i*3 + e]      *4096.f;
        if(e < 11) return qB[m*24 + i*8 + (e-3)]  *4096.f;
        if(e < 17) return qC[m*18 + i*6 + (e-11)] *4096.f;
        return 0.f; };
      qzw[i][0] = make_uint4(pk(qv(0),qv(1)), pk(qv(2),qv(3)), pk(qv(4),qv(5)), pk(qv(6),qv(7)));
      qzw[i][1] = make_uint4(pk(qv(8),qv(9)), pk(qv(10),qv(11)), pk(qv(12),qv(13)), pk(qv(14),qv(15)));
      qzt[i]    = pk(qv(16), 0.f);
    }
  }

  const int g = tid >> 4;
  const int j = jl;
  const int b = blockIdx.x*32 + g;
  const float* xb = x + (size_t)b*4096;
  const float* ub = u + (size_t)b*1024;

  float zr0 = z0ws[(size_t)b*3+0], zr1 = z0ws[(size_t)b*3+1], zr2 = z0ws[(size_t)b*3+2];

  float ua=0.f, uv=0.f, fx0=0.f, fx1=0.f, fx2=0.f, fx3=0.f, epr=0.f;
  const int k0 = 2*j - 3, k1 = 2*j - 2;
  auto preload = [&](int t_){
    ua = (k0 >= 0 && k0 < 8) ? ub[(t_-1)*8 + k0] : 0.f;
    uv = (k1 >= 0 && k1 < 8) ? ub[(t_-1)*8 + k1] : 0.f;
    int e0 = 2*j, e1 = 2*j+1, e2 = 2*j+32, e3 = 2*j+33;
    fx0 = (e0 >= 3 && e0 < 35) ? xb[t_*32 + e0-3] : 0.f;
    fx1 = (e1 >= 3 && e1 < 35) ? xb[t_*32 + e1-3] : 0.f;
    fx2 = (e2 < 35) ? xb[t_*32 + e2-3] : 0.f;
    fx3 = (e3 < 35) ? xb[t_*32 + e3-3] : 0.f;
    epr = (j < 6) ? eps_w[(size_t)(t_-1)*49152 + (size_t)b*6 + j] : 0.f;
  };
  // z-independent staging (x/u slices) into buffer pb
  auto stage_xu = [&](int pb){
    if(j >= 2) S.zxu[pb][g][j] = pk(fx0, fx1);
    if(j < 8){
      int e2 = 2*j+32, e3 = e2+1;
      float d = (e2 < 35) ? fx2 : ((e2 < 43) ? ua : 0.f);
      float e = (e3 < 35) ? fx3 : ((e3 < 43) ? uv : 0.f);
      S.zxu[pb][g][j+16] = pk(d, e);
    }
    if(j >= 2 && j < 6){
      float h = (2*j + 1 < 11) ? uv : 0.f;
      S.zuw[pb][g][j] = pk(ua, h);
    }
  };
  // z-dependent staging (4 words) into buffer pb
  auto stage_z = [&](int pb){
    if(j == 0){
      S.zxu[pb][g][0] = pk(zr0, zr1);
      S.zuw[pb][g][0] = pk(zr0, zr1);
    } else if(j == 1){
      S.zxu[pb][g][1] = pk(zr2, fx1);
      S.zuw[pb][g][1] = pk(zr2, uv);
    }
  };

  __syncthreads();
  preload(1);
  stage_xu(1);
  stage_z(1);
  __syncthreads();

  #pragma unroll 1
  for(int t = 1; t < NT; ++t){
    const int p  = t & 1;
    const int pn = p ^ 1;
    float epsv = epr;
    float u7v  = ua;
    if(t+1 < NT) preload(t+1);

    // ---- interval 1: GEMM1(t) ∥ pth GEMM2(t-1) ∥ stage_xu(t+1) ----
    {
      uint4 Bz[2][2];
      #pragma unroll
      for(int ct=0;ct<2;ct++)
        #pragma unroll
        for(int ks=0;ks<2;ks++)
          Bz[ct][ks] = ldsu4(&S.zxu[p][16*ct + lr][ks*16 + lq*4]);
      #pragma unroll
      for(int rt=0;rt<3;rt++){
        const int R0 = 48*wv + 16*rt;
        unsigned* rowbase;
        int nbase;
        if(R0 < 128){ rowbase = &S.h1F[0][0]; nbase = R0; }
        else if(R0 < 256){ rowbase = &S.h1M[0][0]; nbase = R0 - 128; }
        else { rowbase = &S.h1S[0][0]; nbase = R0 - 256; }
        #pragma unroll
        for(int ct=0;ct<2;ct++){
          f32x4_t acc = {0.f,0.f,0.f,0.f};
          acc = mfma16(A1[rt][0], Bz[ct][0], acc);
          acc = mfma16(A1[rt][1], Bz[ct][1], acc);
          float s0 = sigmoid_f(acc[0] + bias1[rt][0]);
          float s1 = sigmoid_f(acc[1] + bias1[rt][1]);
          float s2 = sigmoid_f(acc[2] + bias1[rt][2]);
          float s3 = sigmoid_f(acc[3] + bias1[rt][3]);
          const int e = 16*ct + lr;
          const int nloc = nbase + lq*4;
          *(uint2*)&rowbase[e*68 + (nloc>>1)] = make_uint2(pk(s0,s1), pk(s2,s3));
        }
      }
    }
    if(wv < 4 && t > 1){
      f32x4_t accp = {0.f,0.f,0.f,0.f};
      #pragma unroll
      for(int ks=0;ks<4;ks++)
        accp = mfma16(Ap[ks], ldsu4(&S.t2b[16*pct + lr][ks*16 + lq*4]), accp);
      const int e = 16*pct + lr;
      float4 o;
      o.x = accp[0] + pb2r[0];
      o.y = accp[1] + pb2r[1];
      o.z = accp[2] + pb2r[2];
      o.w = accp[3] + pb2r[3];
      *(float4*)&out_x[(size_t)(blockIdx.x*32 + e)*4096 + (size_t)(t-1)*32 + 16*prt + lq*4] = o;
    }
    if(t+1 < NT) stage_xu(pn);
    __syncthreads();   // bar A

    // ---- interval 2: L2 MFMAs (waves 0-5); fpsi waves do softmax ----
    {
      const int role2 = wv >> 1;
      if(role2 < 3){
        const int ct2 = wv & 1;
        const int e = 16*ct2 + lr;
        const unsigned* hb = (role2==0) ? &S.h1F[e][0] : (role2==1 ? &S.h1M[e][0] : &S.h1S[e][0]);
        f32x4_t acc = {0.f,0.f,0.f,0.f};
        #pragma unroll
        for(int ks=0;ks<4;ks++)
          acc = mfma16(A2[ks], ldsu4(&hb[ks*16 + lq*4]), acc);
        if(role2 == 0){
          float ev[4];
          #pragma unroll
          for(int rg=0;rg<4;rg++)
            ev[rg] = exp2_f(1.4426950408889634f*(acc[rg] + b2v[rg]));
          float sm = (ev[0]+ev[1]) + (ev[2]+ev[3]);
          sm += __shfl_xor(sm, 16, 64);
          sm += __shfl_xor(sm, 32, 64);
          float rs = rcp_f(sm);
          #pragma unroll
          for(int rg=0;rg<4;rg++)
            S.alphaE[e][lq*4+rg] = ev[rg]*rs;
        } else if(role2 == 1){
          #pragma unroll
          for(int rg=0;rg<4;rg++){
            const int row = lq*4 + rg;
            if(row < 6) S.wmws[e][row] = acc[rg] + b2v[rg];
          }
        } else {
          #pragma unroll
          for(int rg=0;rg<4;rg++){
            const int row = lq*4 + rg;
            if(row < 6) S.wmws[e][6+row] = softplus_f(acc[rg] + b2v[rg]);
          }
        }
      }
    }
    __syncthreads();   // bar B

    // ---- interval 3 (group-local): w, z-update, t2, stage_z(t+1) ----
    float alpha = S.alphaE[g][j];
    if(j < 6){
      float wmu = S.wmws[g][j];
      float wsg = S.wmws[g][6+j];
      *(float2*)&out_w[(size_t)b*1536 + (size_t)t*12 + j*2] = make_float2(wmu, wsg);
      S.wbuf[g][j] = wmu + wsg*epsv;
    }
    if(j >= 5 && j <= 8){
      float a = (j == 5) ? u7v : S.wbuf[g][2*j - 12];
      float c = (2*j + 1 < 17) ? S.wbuf[g][2*j - 10] : 0.f;
      S.zuw[p][g][j] = pk(a, c);
    }
    {
      uint4 a0 = ldsu4(&S.zuw[p][g][0]);
      uint4 a1 = ldsu4(&S.zuw[p][g][4]);
      unsigned a2w = S.zuw[p][g][8];
      float vv0=0.f, vv1=0.f, vv2=0.f;
      #pragma unroll
      for(int i=0;i<3;i++){
        float a = 0.f;
        a = dot4u(qzw[i][0], a0, a);
        a = dot4u(qzw[i][1], a1, a);
        a = fdot2_f(qzt[i], a2w, a);
        a *= alpha;
        if(i==0) vv0 = a; else if(i==1) vv1 = a; else vv2 = a;
      }
      #pragma unroll
      for(int d=1; d<16; d<<=1){
        vv0 += __shfl_xor(vv0, d, 64);
        vv1 += __shfl_xor(vv1, d, 64);
        vv2 += __shfl_xor(vv2, d, 64);
      }
      zr0 = vv0*(1.f/4096.f); zr1 = vv1*(1.f/4096.f); zr2 = vv2*(1.f/4096.f);
    }
    if(j < 3) out_z[(size_t)b*384 + (size_t)t*3 + j] = (j==0? zr0 : (j==1? zr1 : zr2));
    {
      unsigned zp0 = pk(zr0, zr1), zp1 = pk(zr2, 0.f);
      float t2v[8];
      #pragma unroll
      for(int m=0;m<8;m++){
        float a = pb1v[m];
        a = fdot2_f(pw1[m].x, zp0, a);
        a = fdot2_f(pw1[m].y, zp1, a);
        t2v[m] = a;
      }
      *(uint4*)&S.t2b[g][4*j] = make_uint4(pk(t2v[0],t2v[1]), pk(t2v[2],t2v[3]),
                                           pk(t2v[4],t2v[5]), pk(t2v[6],t2v[7]));
    }
    if(t+1 < NT) stage_z(pn);
    __syncthreads();   // bar C
  }

  // ---- epilogue: pth GEMM2 for t = 127 ----
  if(wv < 4){
    f32x4_t accp = {0.f,0.f,0.f,0.f};
    #pragma unroll
    for(int ks=0;ks<4;ks++)
      accp = mfma16(Ap[ks], ldsu4(&S.t2b[16*pct + lr][ks*16 + lq*4]), accp);
    const int e = 16*pct + lr;
    float4 o;
    o.x = accp[0] + pb2r[0];
    o.y = accp[1] + pb2r[1];
    o.z = accp[2] + pb2r[2];
    o.w = accp[3] + pb2r[3];
    *(float4*)&out_x[(size_t)(blockIdx.x*32 + e)*4096 + (size_t)(NT-1)*32 + 16*prt + lq*4] = o;
  }
}

// ---------------------------------------------------------------------------
extern "C" void kernel_launch(void* const* d_in, const int* in_sizes, int n_in,
                              void* d_out, int out_size, void* d_ws, size_t ws_size,
                              hipStream_t stream)
{
  const float* x      = (const float*)d_in[0];
  const float* u      = (const float*)d_in[1];
  const float* eps_w1 = (const float*)d_in[2];
  const float* eps_w  = (const float*)d_in[3];
  const float* Wi_f   = (const float*)d_in[4];
  const float* Wh_f   = (const float*)d_in[5];
  const float* bi_f   = (const float*)d_in[6];
  const float* bh_f   = (const float*)d_in[7];
  const float* Wi_b   = (const float*)d_in[8];
  const float* Wh_b   = (const float*)d_in[9];
  const float* bi_b   = (const float*)d_in[10];
  const float* bh_b   = (const float*)d_in[11];
  const float* pxi_W  = (const float*)d_in[12];
  const float* pxi_b  = (const float*)d_in[13];
  const float* mu_W   = (const float*)d_in[14];
  const float* mu_b   = (const float*)d_in[15];
  const float* sg_W   = (const float*)d_in[16];
  const float* sg_b   = (const float*)d_in[17];
  const float* pl_W1  = (const float*)d_in[18];
  const float* pl_b1  = (const float*)d_in[19];
  const float* pl_W2  = (const float*)d_in[20];
  const float* pl_b2  = (const float*)d_in[21];
  const float* qA     = (const float*)d_in[22];
  const float* qB     = (const float*)d_in[23];
  const float* qC     = (const float*)d_in[24];
  const float* fpsi_W1= (const float*)d_in[25];
  const float* fpsi_b1= (const float*)d_in[26];
  const float* fpsi_W2= (const float*)d_in[27];
  const float* fpsi_b2= (const float*)d_in[28];
  const float* qm_W1  = (const float*)d_in[29];
  const float* qm_b1  = (const float*)d_in[30];
  const float* qm_W2  = (const float*)d_in[31];
  const float* qm_b2  = (const float*)d_in[32];
  const float* qs_W1  = (const float*)d_in[33];
  const float* qs_b1  = (const float*)d_in[34];
  const float* qs_W2  = (const float*)d_in[35];
  const float* qs_b2  = (const float*)d_in[36];
  const float* pth_W1 = (const float*)d_in[37];
  const float* pth_b1 = (const float*)d_in[38];
  const float* pth_W2 = (const float*)d_in[39];
  const float* pth_b2 = (const float*)d_in[40];

  float* ws    = (float*)d_ws;
  float* pre_f = ws;                    // 8192*384
  float* pre_b = ws + 3145728;          // 8192*384
  float* hs_f  = ws + 6291456;          // 8192*128
  float* hs_b  = ws + 7340032;          // 8192*128
  float* z0ws  = ws + 8388608;          // 8192*3

  float* out   = (float*)d_out;
  float* out_x = out;                   // (B,T,32)
  float* out_w = out + 33554432;        // (B,T,6,2)
  float* out_z = out + 46137344;        // (B,T,3)

  k1_pre<<<dim3(128,2), 384, 0, stream>>>(x, Wi_f, bi_f, bh_f, Wi_b, bi_b, bh_b, pre_f, pre_b);
  k2_gru<<<dim3(128,2), 512, 0, stream>>>(pre_f, pre_b, Wh_f, Wh_b, bh_f, bh_b, hs_f, hs_b);
  k3_head<<<256, 512, 0, stream>>>(hs_f, hs_b, pxi_W, pxi_b, mu_W, mu_b, sg_W, sg_b, eps_w1,
                                   pl_W1, pl_b1, pl_W2, pl_b2, pth_W1, pth_b1, pth_W2, pth_b2,
                                   out_x, out_w, out_z, z0ws);
  k4_scan<<<256, 512, 0, stream>>>(x, u, eps_w, z0ws,
                                   fpsi_W1, fpsi_b1, fpsi_W2, fpsi_b2,
                                   qA, qB, qC,
                                   qm_W1, qm_b1, qm_W2, qm_b2,
                                   qs_W1, qs_b1, qs_W2, qs_b2,
                                   pth_W1, pth_b1, pth_W2, pth_b2,
                                   out_x, out_w, out_z);
}

// Round 18
// 426.325 us; speedup vs baseline: 1.0474x; 1.0474x over previous
//
#include <hip/hip_runtime.h>
#include <stdint.h>
#include <stddef.h>

// ---------------------------------------------------------------------------
// BayesFilter: B=8192, T=128, X=32, U=8, Z=3, W=6, H=128, M=16
//  Round-18: best-of recomposition. K4 reverted to round-16 exactly
//  (single-buffer zxu/zuw; r17's double-buffer regressed 338->363).
//  K2 keeps W=40 (r17's verified win). K1/K3 unchanged (round-16).
// ---------------------------------------------------------------------------

typedef __fp16 half2_t __attribute__((ext_vector_type(2)));
typedef __fp16 f16x8_t __attribute__((ext_vector_type(8)));
typedef float  f32x4_t __attribute__((ext_vector_type(4)));

__device__ __forceinline__ float rcp_f(float x){
#if __has_builtin(__builtin_amdgcn_rcpf)
  return __builtin_amdgcn_rcpf(x);
#else
  return 1.0f/x;
#endif
}
__device__ __forceinline__ float exp2_f(float x){
#if __has_builtin(__builtin_amdgcn_exp2f)
  return __builtin_amdgcn_exp2f(x);
#else
  return exp2f(x);
#endif
}
__device__ __forceinline__ float log2_f(float x){
#if __has_builtin(__builtin_amdgcn_logf)
  return __builtin_amdgcn_logf(x);
#else
  return log2f(x);
#endif
}
__device__ __forceinline__ float sigmoid_f(float x){
  return rcp_f(1.0f + exp2_f(-1.4426950408889634f*x));
}
__device__ __forceinline__ float tanh_f(float x){
  x = fminf(fmaxf(x, -15.f), 15.f);
  float t = exp2_f(2.8853900817779268f*x);
  return (t - 1.0f)*rcp_f(t + 1.0f);
}
__device__ __forceinline__ float softplus_f(float x){
  float e = exp2_f(1.4426950408889634f*x);
  float r = 0.6931471805599453f*log2_f(1.0f + e);
  return (x > 15.f) ? x : r;
}
__device__ __forceinline__ unsigned pk(float a, float b){
  union { half2_t h; unsigned u; } cv;
#if __has_builtin(__builtin_amdgcn_cvt_pkrtz)
  cv.h = __builtin_amdgcn_cvt_pkrtz(a, b);
#else
  cv.h.x = (__fp16)a; cv.h.y = (__fp16)b;
#endif
  return cv.u;
}
__device__ __forceinline__ float fdot2_f(unsigned wa, unsigned va, float c){
  union { unsigned u; half2_t h; } A, B;
  A.u = wa; B.u = va;
#if __has_builtin(__builtin_amdgcn_fdot2)
  return __builtin_amdgcn_fdot2(A.h, B.h, c, false);
#else
  return c + (float)A.h.x*(float)B.h.x + (float)A.h.y*(float)B.h.y;
#endif
}
__device__ __forceinline__ float dot4u(uint4 w, uint4 v, float acc){
  acc = fdot2_f(w.x, v.x, acc);
  acc = fdot2_f(w.y, v.y, acc);
  acc = fdot2_f(w.z, v.z, acc);
  acc = fdot2_f(w.w, v.w, acc);
  return acc;
}
__device__ __forceinline__ uint4 ldsu4(const unsigned* p){ return *(const uint4*)p; }
__device__ __forceinline__ f32x4_t mfma16(uint4 a, uint4 b, f32x4_t c){
  union { uint4 u; f16x8_t h; } A, B;
  A.u = a; B.u = b;
  return __builtin_amdgcn_mfma_f32_16x16x32_f16(A.h, B.h, c, 0, 0, 0);
}
__device__ __forceinline__ uint4 pk8(const float* p){
  return make_uint4(pk(p[0],p[1]), pk(p[2],p[3]), pk(p[4],p[5]), pk(p[6],p[7]));
}

#define NB 8192
#define NT 128

// ---------------------------------------------------------------------------
// K1: input projection. 64-row tiles -> 256 blocks.
// ---------------------------------------------------------------------------
__global__ __launch_bounds__(384) void k1_pre(
    const float* __restrict__ x,
    const float* __restrict__ Wi_f, const float* __restrict__ bi_f, const float* __restrict__ bh_f,
    const float* __restrict__ Wi_b, const float* __restrict__ bi_b, const float* __restrict__ bh_b,
    float* __restrict__ pre_f, float* __restrict__ pre_b)
{
  const int tid = threadIdx.x;
  const int dir = blockIdx.y;
  const int tile = blockIdx.x;
  const float* Wi = dir ? Wi_b : Wi_f;
  const float* bi = dir ? bi_b : bi_f;
  const float* bh = dir ? bh_b : bh_f;
  float* pre = dir ? pre_b : pre_f;

  float w[32];
  #pragma unroll
  for(int c=0;c<8;c++){
    float4 a = *(const float4*)&Wi[tid*32 + 4*c];
    w[4*c+0]=a.x; w[4*c+1]=a.y; w[4*c+2]=a.z; w[4*c+3]=a.w;
  }
  float bias = bi[tid] + ((tid < 256) ? bh[tid] : 0.f);

  __shared__ __align__(16) float xs[64][32];
  for(int idx = tid; idx < 2048; idx += 384){
    int rr = idx >> 5, k = idx & 31;
    int i = tile*64 + rr;
    int src = dir ? (NB-1 - i) : i;
    xs[rr][k] = x[(size_t)src*4096 + k];
  }
  __syncthreads();

  for(int rr=0; rr<64; rr++){
    float acc = bias;
    #pragma unroll
    for(int c=0;c<8;c++){
      float4 xv = *(const float4*)&xs[rr][4*c];
      acc += xv.x*w[4*c] + xv.y*w[4*c+1] + xv.z*w[4*c+2] + xv.w*w[4*c+3];
    }
    pre[(size_t)(tile*64+rr)*384 + tid] = acc;
  }
}

// ---------------------------------------------------------------------------
// K2: GRU chunks. O=64, W=40 -> 128 chunks/dir (256 blocks), 104 steps.
// ---------------------------------------------------------------------------
__global__ __launch_bounds__(512, 4) void k2_gru(
    const float* __restrict__ pre_f, const float* __restrict__ pre_b,
    const float* __restrict__ Wh_f, const float* __restrict__ Wh_b,
    const float* __restrict__ bh_f, const float* __restrict__ bh_b,
    float* __restrict__ hs_f, float* __restrict__ hs_b)
{
  const int tid = threadIdx.x;
  const int dir = blockIdx.y;
  const int chunk = blockIdx.x;
  const float* pre = dir ? pre_b : pre_f;
  const float* Wh  = dir ? Wh_b  : Wh_f;
  const float* bh  = dir ? bh_b  : bh_f;
  float* hs = dir ? hs_b : hs_f;

  const int j = tid >> 2;
  const int q = tid & 3;
  const int i_begin = chunk*64;
  int i0 = i_begin - 40; if(i0 < 0) i0 = 0;
  const int i1 = i_begin + 64;

  unsigned wrp[16], wzp[16], wnp[16];
  #pragma unroll
  for(int c=0;c<8;c++){
    float4 a = *(const float4*)&Wh[(size_t)(j      )*128 + 32*q + 4*c];
    float4 b = *(const float4*)&Wh[(size_t)(128 + j)*128 + 32*q + 4*c];
    float4 d = *(const float4*)&Wh[(size_t)(256 + j)*128 + 32*q + 4*c];
    wrp[2*c]   = pk(a.x, a.y); wrp[2*c+1] = pk(a.z, a.w);
    wzp[2*c]   = pk(b.x, b.y); wzp[2*c+1] = pk(b.z, b.w);
    wnp[2*c]   = pk(d.x, d.y); wnp[2*c+1] = pk(d.z, d.w);
  }
  const float bhn = bh[256 + j];

  __shared__ __align__(16) unsigned short hbuf16[2][128];
  __shared__ __align__(16) float pbuf[3][384];
  if(tid < 128) hbuf16[0][tid] = 0;
  if(tid < 384){
    pbuf[0][tid] = pre[(size_t)i0*384 + tid];
    pbuf[1][tid] = pre[(size_t)(i0+1)*384 + tid];
  }
  float h_old = 0.f;
  __syncthreads();

  #pragma unroll 1
  for(int s = i0; s < i1; ++s){
    const int k = s - i0;
    const int cur = k & 1;
    const int p3 = k % 3;
    float pf = 0.f;
    const bool dopf = (tid < 384) && (s+2 < i1);
    if(dopf) pf = pre[(size_t)(s+2)*384 + tid];

    const unsigned* hquart = (const unsigned*)&hbuf16[cur][0] + 16*q;
    uint4 h0 = ldsu4(hquart), h1 = ldsu4(hquart+4), h2 = ldsu4(hquart+8), h3 = ldsu4(hquart+12);

    float ar=0.f, az=0.f, an=0.f;
    ar = dot4u(*(uint4*)&wrp[0], h0, ar); ar = dot4u(*(uint4*)&wrp[4],  h1, ar);
    ar = dot4u(*(uint4*)&wrp[8], h2, ar); ar = dot4u(*(uint4*)&wrp[12], h3, ar);
    az = dot4u(*(uint4*)&wzp[0], h0, az); az = dot4u(*(uint4*)&wzp[4],  h1, az);
    az = dot4u(*(uint4*)&wzp[8], h2, az); az = dot4u(*(uint4*)&wzp[12], h3, az);
    an = dot4u(*(uint4*)&wnp[0], h0, an); an = dot4u(*(uint4*)&wnp[4],  h1, an);
    an = dot4u(*(uint4*)&wnp[8], h2, an); an = dot4u(*(uint4*)&wnp[12], h3, an);

    ar += __shfl_xor(ar, 1, 64); ar += __shfl_xor(ar, 2, 64);
    az += __shfl_xor(az, 1, 64); az += __shfl_xor(az, 2, 64);
    an += __shfl_xor(an, 1, 64); an += __shfl_xor(an, 2, 64);

    float prv = pbuf[p3][j];
    float pzv = pbuf[p3][128 + j];
    float pnv = pbuf[p3][256 + j];
    float r  = sigmoid_f(prv + ar);
    float zg = sigmoid_f(pzv + az);
    float n  = tanh_f(pnv + r*(an + bhn));
    float hnew = n + zg*(h_old - n);
    h_old = hnew;

    if(q == 0){
      union { __fp16 h; unsigned short u; } cv; cv.h = (__fp16)hnew;
      hbuf16[cur^1][j] = cv.u;
      if(s >= i_begin){
        int row = dir ? (NB-1 - s) : s;
        hs[(size_t)row*128 + j] = hnew;
      }
    }
    if(dopf) pbuf[(k+2)%3][tid] = pf;
    __syncthreads();
  }
}

// ---------------------------------------------------------------------------
// K3: t=0 head (round-16: pxi via MFMA).
// ---------------------------------------------------------------------------
__global__ __launch_bounds__(512) void k3_head(
    const float* __restrict__ hs_f, const float* __restrict__ hs_b,
    const float* __restrict__ pxi_W, const float* __restrict__ pxi_b,
    const float* __restrict__ mu_W, const float* __restrict__ mu_b,
    const float* __restrict__ sg_W, const float* __restrict__ sg_b,
    const float* __restrict__ eps_w1,
    const float* __restrict__ pl_W1, const float* __restrict__ pl_b1,
    const float* __restrict__ pl_W2, const float* __restrict__ pl_b2,
    const float* __restrict__ pth_W1, const float* __restrict__ pth_b1,
    const float* __restrict__ pth_W2, const float* __restrict__ pth_b2,
    float* __restrict__ out_x, float* __restrict__ out_w, float* __restrict__ out_z,
    float* __restrict__ z0ws)
{
  __shared__ __align__(16) unsigned hb16[32][132];
  __shared__ __align__(16) float h1[32][132];
  __shared__ __align__(16) float sW_pl1[128][8];
  __shared__ __align__(16) float sW_pt1[128][4];
  __shared__ __align__(16) float wbuf[32][8];
  __shared__ float sb_mu[6], sb_sg[6], sb_pl1[128], sb_pl2[3], sb_pt1[128], sb_pt2[32];

  const int tid = threadIdx.x;
  const int bbase = blockIdx.x*32;
  const int wv = tid >> 6;
  const int ln = tid & 63;
  const int lr = ln & 15;
  const int lq = ln >> 4;

  for(int idx=tid; idx<4096; idx+=512){
    int bb = idx>>7, p = idx&127;
    int c0 = 2*p, c1 = c0+1;
    const size_t base = (size_t)(bbase+bb)*128;
    float a = (c0<128) ? hs_f[base + c0] : hs_b[base + (c0-128)];
    float c = (c1<128) ? hs_f[base + c1] : hs_b[base + (c1-128)];
    hb16[bb][p] = pk(a, c);
  }
  uint4 Apx[8];
  #pragma unroll
  for(int ks=0;ks<8;ks++)
    Apx[ks] = pk8(pxi_W + (size_t)(16*wv + lr)*256 + ks*32 + lq*8);
  float pxb[4];
  #pragma unroll
  for(int rg=0;rg<4;rg++) pxb[rg] = pxi_b[16*wv + lq*4 + rg];

  for(int idx=tid; idx<1024; idx+=512){ int r = idx>>3, c = idx&7; sW_pl1[r][c] = (c<6)? pl_W1[r*6+c] : 0.f; }
  { int r = tid>>2, c = tid&3; sW_pt1[r][c] = (c<3)? pth_W1[r*3+c] : 0.f; }
  if(tid<128){ sb_pl1[tid]=pl_b1[tid]; sb_pt1[tid]=pth_b1[tid]; }
  if(tid<6){ sb_mu[tid]=mu_b[tid]; sb_sg[tid]=sg_b[tid]; }
  if(tid<3) sb_pl2[tid]=pl_b2[tid];
  if(tid<32) sb_pt2[tid]=pth_b2[tid];
  __syncthreads();

  {
    #pragma unroll
    for(int ct=0;ct<2;ct++){
      f32x4_t acc = {0.f,0.f,0.f,0.f};
      #pragma unroll
      for(int ks=0;ks<8;ks++)
        acc = mfma16(Apx[ks], ldsu4(&hb16[16*ct + lr][ks*16 + lq*4]), acc);
      const int e = 16*ct + lr;
      #pragma unroll
      for(int rg=0;rg<4;rg++)
        h1[e][16*wv + lq*4 + rg] = fmaxf(acc[rg] + pxb[rg], 0.f);
    }
  }
  __syncthreads();

  const int g = tid >> 4;
  const int j = tid & 15;
  const int b = bbase + g;

  float muv = 0.f, sgv = 0.f;
  if(j < 12){
    bool isS = (j >= 6); int o = isS ? (j-6) : j;
    const float4* wrow = (const float4*)((isS ? sg_W : mu_W) + (size_t)o*128);
    const float4* hrow = (const float4*)&h1[g][0];
    float acc = isS ? sb_sg[o] : sb_mu[o];
    #pragma unroll 8
    for(int kk=0;kk<32;kk++){
      float4 wv_ = wrow[kk], hv = hrow[kk];
      acc += wv_.x*hv.x + wv_.y*hv.y + wv_.z*hv.z + wv_.w*hv.w;
    }
    if(isS) sgv = softplus_f(acc); else muv = acc;
  }
  const int lw = tid & 63; const int gb = lw & 48;
  int src = gb + ((j < 6) ? (j + 6) : j);
  float sgp = __shfl(sgv, src, 64);
  if(j < 6){
    float w1v = muv + sgp*eps_w1[(size_t)b*6 + j];
    wbuf[g][j] = w1v;
    out_w[(size_t)b*1536 + j*2]     = muv;
    out_w[(size_t)b*1536 + j*2 + 1] = sgp;
  }
  if(j == 6 || j == 7) wbuf[g][j] = 0.f;

  {
    const float4* wb = (const float4*)&wbuf[g][0];
    float4 b0 = wb[0], b1 = wb[1];
    #pragma unroll
    for(int m=0;m<8;m++){
      int r = 8*j + m;
      float4 w0 = *(const float4*)&sW_pl1[r][0];
      float4 w1 = *(const float4*)&sW_pl1[r][4];
      h1[g][r] = sb_pl1[r]
        + w0.x*b0.x + w0.y*b0.y + w0.z*b0.z + w0.w*b0.w
        + w1.x*b1.x + w1.y*b1.y + w1.z*b1.z + w1.w*b1.w;
    }
  }
  float z0v = 0.f;
  if(j < 3){
    const float4* wrow = (const float4*)(pl_W2 + (size_t)j*128);
    const float4* hrow = (const float4*)&h1[g][0];
    float acc = sb_pl2[j];
    #pragma unroll 8
    for(int kk=0;kk<32;kk++){
      float4 wv_ = wrow[kk], hv = hrow[kk];
      acc += wv_.x*hv.x + wv_.y*hv.y + wv_.z*hv.z + wv_.w*hv.w;
    }
    z0v = acc;
    out_z[(size_t)b*384 + j] = z0v;
    z0ws[(size_t)b*3 + j] = z0v;
  }
  float zz0 = __shfl(z0v, gb+0, 64);
  float zz1 = __shfl(z0v, gb+1, 64);
  float zz2 = __shfl(z0v, gb+2, 64);
  #pragma unroll
  for(int m=0;m<8;m++){
    int r = 8*j + m;
    float4 wv_ = *(const float4*)&sW_pt1[r][0];
    h1[g][r] = sb_pt1[r] + wv_.x*zz0 + wv_.y*zz1 + wv_.z*zz2;
  }
  {
    float a1 = sb_pt2[j], a2 = sb_pt2[j+16];
    const float4* hrow = (const float4*)&h1[g][0];
    const float4* wA = (const float4*)(pth_W2 + (size_t)j*128);
    const float4* wB = (const float4*)(pth_W2 + (size_t)(j+16)*128);
    #pragma unroll 8
    for(int kk=0;kk<32;kk++){
      float4 hv = hrow[kk]; float4 a = wA[kk]; float4 c = wB[kk];
      a1 += a.x*hv.x + a.y*hv.y + a.z*hv.z + a.w*hv.w;
      a2 += c.x*hv.x + c.y*hv.y + c.z*hv.z + c.w*hv.w;
    }
    out_x[(size_t)b*4096 + j]      = a1;
    out_x[(size_t)b*4096 + j + 16] = a2;
  }
}

// ---------------------------------------------------------------------------
// K4: t = 1..127 scan (exact round-16 version: single-buffer zxu/zuw,
// 3 barriers/step, softmax in interval 2).
// ---------------------------------------------------------------------------
struct __align__(16) K4LDS {
  unsigned zxu[32][36];
  unsigned zuw[32][12];
  unsigned h1F[32][68];
  unsigned h1M[32][68];
  unsigned h1S[32][68];
  unsigned t2b[32][68];
  float alphaE[32][21];
  float wmws[32][21];
  float wbuf[32][8];
};
static_assert(sizeof(K4LDS) <= 65536, "K4 LDS over 64KB");

__global__ __launch_bounds__(512) void k4_scan(
    const float* __restrict__ x, const float* __restrict__ u, const float* __restrict__ eps_w,
    const float* __restrict__ z0ws,
    const float* __restrict__ fpsi_W1, const float* __restrict__ fpsi_b1,
    const float* __restrict__ fpsi_W2, const float* __restrict__ fpsi_b2,
    const float* __restrict__ qA, const float* __restrict__ qB, const float* __restrict__ qC,
    const float* __restrict__ qm_W1, const float* __restrict__ qm_b1,
    const float* __restrict__ qm_W2, const float* __restrict__ qm_b2,
    const float* __restrict__ qs_W1, const float* __restrict__ qs_b1,
    const float* __restrict__ qs_W2, const float* __restrict__ qs_b2,
    const float* __restrict__ pth_W1, const float* __restrict__ pth_b1,
    const float* __restrict__ pth_W2, const float* __restrict__ pth_b2,
    float* __restrict__ out_x, float* __restrict__ out_w, float* __restrict__ out_z)
{
  __shared__ K4LDS S;
  const int tid = threadIdx.x;
  const int jl = tid & 15;
  const int wv = tid >> 6;
  const int ln = tid & 63;
  const int lr = ln & 15;
  const int lq = ln >> 4;

  {
    { unsigned* z1 = &S.zxu[0][0]; for(int idx=tid; idx<32*36; idx+=512) z1[idx] = 0u; }
    { unsigned* z2 = &S.zuw[0][0]; for(int idx=tid; idx<32*12; idx+=512) z2[idx] = 0u; }
  }

  auto stackA = [&](int R, int k)->float{
    if(k >= 43) return 0.f;
    if(R < 128){
      if(k < 3)   return fpsi_W1[R*11 + k];
      if(k >= 35) return fpsi_W1[R*11 + 3 + (k - 35)];
      return 0.f;
    }
    if(R < 256) return qm_W1[(size_t)(R-128)*43 + k];
    return qs_W1[(size_t)(R-256)*43 + k];
  };
  uint4 A1[3][2]; float bias1[3][4];
  #pragma unroll
  for(int rt=0;rt<3;rt++){
    const int R0 = 48*wv + 16*rt;
    #pragma unroll
    for(int ks=0;ks<2;ks++){
      float f[8];
      #pragma unroll
      for(int e2=0;e2<8;e2++) f[e2] = stackA(R0 + lr, 32*ks + lq*8 + e2);
      A1[rt][ks] = make_uint4(pk(f[0],f[1]),pk(f[2],f[3]),pk(f[4],f[5]),pk(f[6],f[7]));
    }
    #pragma unroll
    for(int rg=0;rg<4;rg++){
      int R = R0 + lq*4 + rg;
      bias1[rt][rg] = (R<128) ? fpsi_b1[R] : (R<256 ? qm_b1[R-128] : qs_b1[R-256]);
    }
  }
  uint4 A2[4] = {};
  float b2v[4] = {0.f,0.f,0.f,0.f};
  {
    const int role2 = wv >> 1;
    if(role2 == 0){
      const float* wr_ = fpsi_W2 + (size_t)lr*128;
      #pragma unroll
      for(int ks=0;ks<4;ks++) A2[ks] = pk8(wr_ + ks*32 + lq*8);
      #pragma unroll
      for(int rg=0;rg<4;rg++) b2v[rg] = fpsi_b2[lq*4+rg];
    } else if(role2 == 1){
      if(lr < 6){
        const float* wr_ = qm_W2 + (size_t)lr*128;
        #pragma unroll
        for(int ks=0;ks<4;ks++) A2[ks] = pk8(wr_ + ks*32 + lq*8);
      }
      #pragma unroll
      for(int rg=0;rg<4;rg++){ int row = lq*4+rg; b2v[rg] = (row<6)? qm_b2[row] : 0.f; }
    } else if(role2 == 2){
      if(lr < 6){
        const float* wr_ = qs_W2 + (size_t)lr*128;
        #pragma unroll
        for(int ks=0;ks<4;ks++) A2[ks] = pk8(wr_ + ks*32 + lq*8);
      }
      #pragma unroll
      for(int rg=0;rg<4;rg++){ int row = lq*4+rg; b2v[rg] = (row<6)? qs_b2[row] : 0.f; }
    }
  }
  const int prt = wv & 1, pct = (wv >> 1) & 1;
  uint4 Ap[4] = {};
  float pb2r[4] = {0.f,0.f,0.f,0.f};
  if(wv < 4){
    #pragma unroll
    for(int ks=0;ks<4;ks++){
      const float* wr_ = pth_W2 + (size_t)(16*prt + lr)*128 + ks*32 + lq*8;
      Ap[ks] = pk8(wr_);
    }
    #pragma unroll
    for(int rg=0;rg<4;rg++) pb2r[rg] = pth_b2[16*prt + lq*4 + rg];
  }
  uint2 pw1[8]; float pb1v[8];
  #pragma unroll
  for(int m=0;m<8;m++){
    const float* prow = pth_W1 + (size_t)(8*jl + m)*3;
    pw1[m] = make_uint2(pk(prow[0],prow[1]), pk(prow[2],0.f));
    pb1v[m] = pth_b1[8*jl + m];
  }
  uint4 qzw[3][2]; unsigned qzt[3];
  {
    const int m = jl;
    #pragma unroll
    for(int i=0;i<3;i++){
      auto qv = [&](int e)->float{
        if(e < 3)  return qA[m*9  + i*3 + e]      *4096.f;
        if(e < 11) return qB[m*24 + i*8 + (e-3)]  *4096.f;
        if(e < 17) return qC[m*18 + i*6 + (e-11)] *4096.f;
        return 0.f; };
      qzw[i][0] = make_uint4(pk(qv(0),qv(1)), pk(qv(2),qv(3)), pk(qv(4),qv(5)), pk(qv(6),qv(7)));
      qzw[i][1] = make_uint4(pk(qv(8),qv(9)), pk(qv(10),qv(11)), pk(qv(12),qv(13)), pk(qv(14),qv(15)));
      qzt[i]    = pk(qv(16), 0.f);
    }
  }

  const int g = tid >> 4;
  const int j = jl;
  const int b = blockIdx.x*32 + g;
  const float* xb = x + (size_t)b*4096;
  const float* ub = u + (size_t)b*1024;

  float zr0 = z0ws[(size_t)b*3+0], zr1 = z0ws[(size_t)b*3+1], zr2 = z0ws[(size_t)b*3+2];

  float ua=0.f, uv=0.f, fx0=0.f, fx1=0.f, fx2=0.f, fx3=0.f, epr=0.f;
  const int k0 = 2*j - 3, k1 = 2*j - 2;
  auto preload = [&](int t_){
    ua = (k0 >= 0 && k0 < 8) ? ub[(t_-1)*8 + k0] : 0.f;
    uv = (k1 >= 0 && k1 < 8) ? ub[(t_-1)*8 + k1] : 0.f;
    int e0 = 2*j, e1 = 2*j+1, e2 = 2*j+32, e3 = 2*j+33;
    fx0 = (e0 >= 3 && e0 < 35) ? xb[t_*32 + e0-3] : 0.f;
    fx1 = (e1 >= 3 && e1 < 35) ? xb[t_*32 + e1-3] : 0.f;
    fx2 = (e2 < 35) ? xb[t_*32 + e2-3] : 0.f;
    fx3 = (e3 < 35) ? xb[t_*32 + e3-3] : 0.f;
    epr = (j < 6) ? eps_w[(size_t)(t_-1)*49152 + (size_t)b*6 + j] : 0.f;
  };
  auto stage_inputs = [&](){
    auto zval = [&](int e)->float{ return (e==0)? zr0 : ((e==1)? zr1 : zr2); };
    int e0 = 2*j, e1 = e0+1;
    float a = (e0 < 3) ? zval(e0) : fx0;
    float c = (e1 < 3) ? zval(e1) : fx1;
    S.zxu[g][j] = pk(a, c);
    if(j < 8){
      int e2 = 2*j+32, e3 = e2+1;
      float d = (e2 < 35) ? fx2 : ((e2 < 43) ? ua : 0.f);
      float e = (e3 < 35) ? fx3 : ((e3 < 43) ? uv : 0.f);
      S.zxu[g][j+16] = pk(d, e);
    }
    if(j < 6){
      int e4 = 2*j, e5 = e4+1;
      float f = (e4 < 3) ? zval(e4) : ua;
      float h = (e5 < 3) ? zval(e5) : ((e5 < 11) ? uv : 0.f);
      S.zuw[g][j] = pk(f, h);
    }
  };

  __syncthreads();
  preload(1);
  stage_inputs();
  __syncthreads();

  #pragma unroll 1
  for(int t = 1; t < NT; ++t){
    float epsv = epr;
    float u7v  = ua;
    if(t+1 < NT) preload(t+1);

    // ---- interval 1: GEMM1(t) ∥ pth GEMM2(t-1) ----
    {
      uint4 Bz[2][2];
      #pragma unroll
      for(int ct=0;ct<2;ct++)
        #pragma unroll
        for(int ks=0;ks<2;ks++)
          Bz[ct][ks] = ldsu4(&S.zxu[16*ct + lr][ks*16 + lq*4]);
      #pragma unroll
      for(int rt=0;rt<3;rt++){
        const int R0 = 48*wv + 16*rt;
        unsigned* rowbase;
        int nbase;
        if(R0 < 128){ rowbase = &S.h1F[0][0]; nbase = R0; }
        else if(R0 < 256){ rowbase = &S.h1M[0][0]; nbase = R0 - 128; }
        else { rowbase = &S.h1S[0][0]; nbase = R0 - 256; }
        #pragma unroll
        for(int ct=0;ct<2;ct++){
          f32x4_t acc = {0.f,0.f,0.f,0.f};
          acc = mfma16(A1[rt][0], Bz[ct][0], acc);
          acc = mfma16(A1[rt][1], Bz[ct][1], acc);
          float s0 = sigmoid_f(acc[0] + bias1[rt][0]);
          float s1 = sigmoid_f(acc[1] + bias1[rt][1]);
          float s2 = sigmoid_f(acc[2] + bias1[rt][2]);
          float s3 = sigmoid_f(acc[3] + bias1[rt][3]);
          const int e = 16*ct + lr;
          const int nloc = nbase + lq*4;
          *(uint2*)&rowbase[e*68 + (nloc>>1)] = make_uint2(pk(s0,s1), pk(s2,s3));
        }
      }
    }
    if(wv < 4 && t > 1){
      f32x4_t accp = {0.f,0.f,0.f,0.f};
      #pragma unroll
      for(int ks=0;ks<4;ks++)
        accp = mfma16(Ap[ks], ldsu4(&S.t2b[16*pct + lr][ks*16 + lq*4]), accp);
      const int e = 16*pct + lr;
      float4 o;
      o.x = accp[0] + pb2r[0];
      o.y = accp[1] + pb2r[1];
      o.z = accp[2] + pb2r[2];
      o.w = accp[3] + pb2r[3];
      *(float4*)&out_x[(size_t)(blockIdx.x*32 + e)*4096 + (size_t)(t-1)*32 + 16*prt + lq*4] = o;
    }
    __syncthreads();   // bar A

    // ---- interval 2: L2 MFMAs (waves 0-5); fpsi waves also do softmax ----
    {
      const int role2 = wv >> 1;
      if(role2 < 3){
        const int ct2 = wv & 1;
        const int e = 16*ct2 + lr;
        const unsigned* hb = (role2==0) ? &S.h1F[e][0] : (role2==1 ? &S.h1M[e][0] : &S.h1S[e][0]);
        f32x4_t acc = {0.f,0.f,0.f,0.f};
        #pragma unroll
        for(int ks=0;ks<4;ks++)
          acc = mfma16(A2[ks], ldsu4(&hb[ks*16 + lq*4]), acc);
        if(role2 == 0){
          float ev[4];
          #pragma unroll
          for(int rg=0;rg<4;rg++)
            ev[rg] = exp2_f(1.4426950408889634f*(acc[rg] + b2v[rg]));
          float sm = (ev[0]+ev[1]) + (ev[2]+ev[3]);
          sm += __shfl_xor(sm, 16, 64);
          sm += __shfl_xor(sm, 32, 64);
          float rs = rcp_f(sm);
          #pragma unroll
          for(int rg=0;rg<4;rg++)
            S.alphaE[e][lq*4+rg] = ev[rg]*rs;
        } else if(role2 == 1){
          #pragma unroll
          for(int rg=0;rg<4;rg++){
            const int row = lq*4 + rg;
            if(row < 6) S.wmws[e][row] = acc[rg] + b2v[rg];
          }
        } else {
          #pragma unroll
          for(int rg=0;rg<4;rg++){
            const int row = lq*4 + rg;
            if(row < 6) S.wmws[e][6+row] = softplus_f(acc[rg] + b2v[rg]);
          }
        }
      }
    }
    __syncthreads();   // bar B

    // ---- interval 3 (group-local): w, z-update, t2, stage(t+1) ----
    float alpha = S.alphaE[g][j];
    if(j < 6){
      float wmu = S.wmws[g][j];
      float wsg = S.wmws[g][6+j];
      *(float2*)&out_w[(size_t)b*1536 + (size_t)t*12 + j*2] = make_float2(wmu, wsg);
      S.wbuf[g][j] = wmu + wsg*epsv;
    }
    if(j >= 5 && j <= 8){
      float a = (j == 5) ? u7v : S.wbuf[g][2*j - 12];
      float c = (2*j + 1 < 17) ? S.wbuf[g][2*j - 10] : 0.f;
      S.zuw[g][j] = pk(a, c);
    }
    {
      uint4 a0 = ldsu4(&S.zuw[g][0]);
      uint4 a1 = ldsu4(&S.zuw[g][4]);
      unsigned a2w = S.zuw[g][8];
      float vv0=0.f, vv1=0.f, vv2=0.f;
      #pragma unroll
      for(int i=0;i<3;i++){
        float a = 0.f;
        a = dot4u(qzw[i][0], a0, a);
        a = dot4u(qzw[i][1], a1, a);
        a = fdot2_f(qzt[i], a2w, a);
        a *= alpha;
        if(i==0) vv0 = a; else if(i==1) vv1 = a; else vv2 = a;
      }
      #pragma unroll
      for(int d=1; d<16; d<<=1){
        vv0 += __shfl_xor(vv0, d, 64);
        vv1 += __shfl_xor(vv1, d, 64);
        vv2 += __shfl_xor(vv2, d, 64);
      }
      zr0 = vv0*(1.f/4096.f); zr1 = vv1*(1.f/4096.f); zr2 = vv2*(1.f/4096.f);
    }
    if(j < 3) out_z[(size_t)b*384 + (size_t)t*3 + j] = (j==0? zr0 : (j==1? zr1 : zr2));
    {
      unsigned zp0 = pk(zr0, zr1), zp1 = pk(zr2, 0.f);
      float t2v[8];
      #pragma unroll
      for(int m=0;m<8;m++){
        float a = pb1v[m];
        a = fdot2_f(pw1[m].x, zp0, a);
        a = fdot2_f(pw1[m].y, zp1, a);
        t2v[m] = a;
      }
      *(uint4*)&S.t2b[g][4*j] = make_uint4(pk(t2v[0],t2v[1]), pk(t2v[2],t2v[3]),
                                           pk(t2v[4],t2v[5]), pk(t2v[6],t2v[7]));
    }
    if(t+1 < NT) stage_inputs();
    __syncthreads();   // bar C
  }

  // ---- epilogue: pth GEMM2 for t = 127 ----
  if(wv < 4){
    f32x4_t accp = {0.f,0.f,0.f,0.f};
    #pragma unroll
    for(int ks=0;ks<4;ks++)
      accp = mfma16(Ap[ks], ldsu4(&S.t2b[16*pct + lr][ks*16 + lq*4]), accp);
    const int e = 16*pct + lr;
    float4 o;
    o.x = accp[0] + pb2r[0];
    o.y = accp[1] + pb2r[1];
    o.z = accp[2] + pb2r[2];
    o.w = accp[3] + pb2r[3];
    *(float4*)&out_x[(size_t)(blockIdx.x*32 + e)*4096 + (size_t)(NT-1)*32 + 16*prt + lq*4] = o;
  }
}

// ---------------------------------------------------------------------------
extern "C" void kernel_launch(void* const* d_in, const int* in_sizes, int n_in,
                              void* d_out, int out_size, void* d_ws, size_t ws_size,
                              hipStream_t stream)
{
  const float* x      = (const float*)d_in[0];
  const float* u      = (const float*)d_in[1];
  const float* eps_w1 = (const float*)d_in[2];
  const float* eps_w  = (const float*)d_in[3];
  const float* Wi_f   = (const float*)d_in[4];
  const float* Wh_f   = (const float*)d_in[5];
  const float* bi_f   = (const float*)d_in[6];
  const float* bh_f   = (const float*)d_in[7];
  const float* Wi_b   = (const float*)d_in[8];
  const float* Wh_b   = (const float*)d_in[9];
  const float* bi_b   = (const float*)d_in[10];
  const float* bh_b   = (const float*)d_in[11];
  const float* pxi_W  = (const float*)d_in[12];
  const float* pxi_b  = (const float*)d_in[13];
  const float* mu_W   = (const float*)d_in[14];
  const float* mu_b   = (const float*)d_in[15];
  const float* sg_W   = (const float*)d_in[16];
  const float* sg_b   = (const float*)d_in[17];
  const float* pl_W1  = (const float*)d_in[18];
  const float* pl_b1  = (const float*)d_in[19];
  const float* pl_W2  = (const float*)d_in[20];
  const float* pl_b2  = (const float*)d_in[21];
  const float* qA     = (const float*)d_in[22];
  const float* qB     = (const float*)d_in[23];
  const float* qC     = (const float*)d_in[24];
  const float* fpsi_W1= (const float*)d_in[25];
  const float* fpsi_b1= (const float*)d_in[26];
  const float* fpsi_W2= (const float*)d_in[27];
  const float* fpsi_b2= (const float*)d_in[28];
  const float* qm_W1  = (const float*)d_in[29];
  const float* qm_b1  = (const float*)d_in[30];
  const float* qm_W2  = (const float*)d_in[31];
  const float* qm_b2  = (const float*)d_in[32];
  const float* qs_W1  = (const float*)d_in[33];
  const float* qs_b1  = (const float*)d_in[34];
  const float* qs_W2  = (const float*)d_in[35];
  const float* qs_b2  = (const float*)d_in[36];
  const float* pth_W1 = (const float*)d_in[37];
  const float* pth_b1 = (const float*)d_in[38];
  const float* pth_W2 = (const float*)d_in[39];
  const float* pth_b2 = (const float*)d_in[40];

  float* ws    = (float*)d_ws;
  float* pre_f = ws;                    // 8192*384
  float* pre_b = ws + 3145728;          // 8192*384
  float* hs_f  = ws + 6291456;          // 8192*128
  float* hs_b  = ws + 7340032;          // 8192*128
  float* z0ws  = ws + 8388608;          // 8192*3

  float* out   = (float*)d_out;
  float* out_x = out;                   // (B,T,32)
  float* out_w = out + 33554432;        // (B,T,6,2)
  float* out_z = out + 46137344;        // (B,T,3)

  k1_pre<<<dim3(128,2), 384, 0, stream>>>(x, Wi_f, bi_f, bh_f, Wi_b, bi_b, bh_b, pre_f, pre_b);
  k2_gru<<<dim3(128,2), 512, 0, stream>>>(pre_f, pre_b, Wh_f, Wh_b, bh_f, bh_b, hs_f, hs_b);
  k3_head<<<256, 512, 0, stream>>>(hs_f, hs_b, pxi_W, pxi_b, mu_W, mu_b, sg_W, sg_b, eps_w1,
                                   pl_W1, pl_b1, pl_W2, pl_b2, pth_W1, pth_b1, pth_W2, pth_b2,
                                   out_x, out_w, out_z, z0ws);
  k4_scan<<<256, 512, 0, stream>>>(x, u, eps_w, z0ws,
                                   fpsi_W1, fpsi_b1, fpsi_W2, fpsi_b2,
                                   qA, qB, qC,
                                   qm_W1, qm_b1, qm_W2, qm_b2,
                                   qs_W1, qs_b1, qs_W2, qs_b2,
                                   pth_W1, pth_b1, pth_W2, pth_b2,
                                   out_x, out_w, out_z);
}